// Round 10
// baseline (125.038 us; speedup 1.0000x reference)
//
#include <hip/hip_runtime.h>

// SKA: per-pixel dynamic depthwise 5x5 conv
// x: [B=8, C=256, H=64, W=64] f32
// w: [B=8, G=8, K2=25, H=64, W=64] f32
// out[b,c,h,w] = sum_k x[b,c,h+k/5-2,w+k%5-2] * w[b,g,k,h,w], g = c/32
//
// Design R (round 17): register-direct, ZERO LDS, ZERO barriers.
// Round-16 post-mortem: P2b (no-drain barriers) == P2 => barrier-DRAIN
// theory dead. Nine rounds: the whole barrier-phased LDS-staging family
// (H3/H4/H5/P/P2/P2b) is pinned at 29-36us vs ~16-20us HBM floor with all
// pipes underused (VALU<=18%, DS<=20%, HBM 50-65%). Residual = barrier
// convoy: 4 waves/block stall together at each phase edge, only 1 other
// block/CU to cover. The untested axis: no inter-thread sharing at all.
// This design:
//  - Each thread loads its own 5-row x 8-col window per channel directly
//    from global: per row b128(mid, cols wcol..wcol+3) + b64(left, wcol-2)
//    + b64(right, wcol+4). 5-8x address redundancy is L1/L2-absorbed
//    (per-wave/channel working set ~2KB); HBM-unique bytes ~98MB unchanged.
//  - NO LDS, NO barriers: waves free-run; a stalled wave never blocks the
//    other 7 on the CU. All staging/guard/swo machinery deleted.
//  - OOB: wk masked ONCE at load (VGPR-resident thereafter): wk[k].t = 0
//    iff row h+k/5-2 or col wcol+t+k%5-2 OOB => OOB taps contribute exact
//    0*x = 0, bit-identical to jnp.pad. Halo loads use clamped in-bounds
//    addresses (j==0: left->col0; j==15: right->col60; rows clamped to
//    [0,63]) so garbage is finite and always w-masked.
//  - 1-deep channel prefetch (A/B reg sets): ch i+1's 15 loads in flight
//    under ch i's 100 FMAs (+ cross-wave overlap). Channel loop unroll-2 =>
//    all A/B indices static (SROA-safe, round-3 lesson).
//  - Keep P2 grid: 512 blocks (2/CU), blockIdx=[half|b|g|band], halves
//    stride-256 => same XCD => shared w slice L2/L3-hot.
// FMA order: di outer, dj inner, per t — identical to P2 => absmax 0.0.
// Tripwires: VGPR ~200-230 (=256 => spill, check WRITE_SIZE >> 33MB);
// LDS_Block_Size must be 0. Flat harness (>=104us) => free-running axis
// dead too => declare practical plateau next round.

#define B_ 8
#define C_ 256
#define G_ 8
#define CG_ 32
#define H_ 64
#define W_ 64
#define K2_ 25
#define HW_ (H_ * W_)
#define NCHB 16             // channels per block (half group)

// load one channel's 5-row x 8-col window (15 loads, 40 words)
#define LOADCH(M, L, R, XP)                                \
  _Pragma("unroll") for (int di = 0; di < 5; ++di) {       \
    const float* rp = (XP) + rofs[di];                     \
    M[di] = *(const float4*)(rp + wcol);                   \
    L[di] = *(const float2*)(rp + cl);                     \
    R[di] = *(const float2*)(rp + cr);                     \
  }

// compute one channel (100 FMAs) from its window regs and store
#define COMPSTORE(M, L, R, OP)                             \
  {                                                        \
    float acc0 = 0.f, acc1 = 0.f, acc2 = 0.f, acc3 = 0.f;  \
    _Pragma("unroll") for (int di = 0; di < 5; ++di) {     \
      alignas(16) float xr[8];                             \
      xr[0] = L[di].x; xr[1] = L[di].y;                    \
      xr[2] = M[di].x; xr[3] = M[di].y;                    \
      xr[4] = M[di].z; xr[5] = M[di].w;                    \
      xr[6] = R[di].x; xr[7] = R[di].y;                    \
      _Pragma("unroll") for (int dj = 0; dj < 5; ++dj) {   \
        const float4 wv = wk[di * 5 + dj];                 \
        acc0 = fmaf(xr[dj + 0], wv.x, acc0);               \
        acc1 = fmaf(xr[dj + 1], wv.y, acc1);               \
        acc2 = fmaf(xr[dj + 2], wv.z, acc2);               \
        acc3 = fmaf(xr[dj + 3], wv.w, acc3);               \
      }                                                    \
    }                                                      \
    float4 o;                                              \
    o.x = acc0; o.y = acc1; o.z = acc2; o.w = acc3;        \
    *(float4*)(OP) = o;                                    \
  }

__global__ __launch_bounds__(256, 2) void ska_kernel(
    const float* __restrict__ x, const float* __restrict__ w,
    float* __restrict__ out) {
  const int tid = threadIdx.x;
  const int lr = tid >> 4;   // output row within band (0..15)
  const int j = tid & 15;    // column quad (cols 4j..4j+3)
  const int wcol = j * 4;

  // blockIdx = [half(1) | b(3) | g(3) | band(2)], 512 blocks = 2 per CU.
  const int blk = blockIdx.x;
  const int band = blk & 3;
  const int g = (blk >> 2) & 7;
  const int b = (blk >> 5) & 7;
  const int half = blk >> 8;  // 0/1: which 16 channels of the group

  const int h0 = band * 16;
  const int h = h0 + lr;

  // clamped row word-offsets for taps di=0..4 (OOB rows w-masked below)
  int rofs[5];
#pragma unroll
  for (int di = 0; di < 5; ++di) {
    const int rr = min(max(h + di - 2, 0), H_ - 1);
    rofs[di] = rr * W_;
  }
  // clamped halo column offsets (edge garbage is w-masked, stays finite)
  const int cl = (j == 0) ? 0 : (wcol - 2);
  const int cr = (j == 15) ? (W_ - 4) : (wcol + 4);

  const size_t chanbase = (size_t)(b * C_ + g * CG_ + half * NCHB) * HW_;
  const float* xp = x + chanbase;
  float* op = out + chanbase + (size_t)h * W_ + wcol;

  float4 AM[5], BM[5];
  float2 AL[5], BL[5], AR[5], BR[5];

  // ---- issue channel 0 window first (flies under the wk burst) ----
  LOADCH(AM, AL, AR, xp)

  // ---- load all 25 w quads, mask OOB taps ONCE (VGPR-resident) ----
  const float* wb =
      w + (size_t)(b * G_ + g) * K2_ * HW_ + (size_t)h * W_ + wcol;
  float4 wk[K2_];
#pragma unroll
  for (int k = 0; k < K2_; ++k) {
    float4 a = *(const float4*)(wb + (size_t)k * HW_);
    const int di = k / 5, dj = k % 5;
    const bool rok = (unsigned)(h + di - 2) < (unsigned)H_;
    a.x = (rok && (unsigned)(wcol + 0 + dj - 2) < (unsigned)W_) ? a.x : 0.0f;
    a.y = (rok && (unsigned)(wcol + 1 + dj - 2) < (unsigned)W_) ? a.y : 0.0f;
    a.z = (rok && (unsigned)(wcol + 2 + dj - 2) < (unsigned)W_) ? a.z : 0.0f;
    a.w = (rok && (unsigned)(wcol + 3 + dj - 2) < (unsigned)W_) ? a.w : 0.0f;
    wk[k] = a;
  }

  // ---- 16 channels, unroll-2, 1-deep A/B prefetch, no sync anywhere ----
  for (int it = 0; it < NCHB / 2; ++it) {
    LOADCH(BM, BL, BR, xp + HW_)        // ch 2it+1 in flight
    COMPSTORE(AM, AL, AR, op)           // ch 2it
    if (it < NCHB / 2 - 1) {
      LOADCH(AM, AL, AR, xp + 2 * HW_)  // ch 2it+2 in flight
    }
    COMPSTORE(BM, BL, BR, op + HW_)     // ch 2it+1
    xp += 2 * HW_;
    op += 2 * HW_;
  }
}

extern "C" void kernel_launch(void* const* d_in, const int* in_sizes, int n_in,
                              void* d_out, int out_size, void* d_ws,
                              size_t ws_size, hipStream_t stream) {
  const float* x = (const float*)d_in[0];
  const float* w = (const float*)d_in[1];
  float* out = (float*)d_out;
  // grid: 2 halves * 8 b * 8 g * 4 bands = 512 blocks of 256 threads
  ska_kernel<<<dim3(512), dim3(256), 0, stream>>>(x, w, out);
}

// Round 11
// 108.696 us; speedup vs baseline: 1.1504x; 1.1504x over previous
//
#include <hip/hip_runtime.h>

// SKA: per-pixel dynamic depthwise 5x5 conv
// x: [B=8, C=256, H=64, W=64] f32
// w: [B=8, G=8, K2=25, H=64, W=64] f32
// out[b,c,h,w] = sum_k x[b,c,h+k/5-2,w+k%5-2] * w[b,g,k,h,w], g = c/32
//
// Design P3 (round 18): P2b + ALL reads issued up front (max-MLP).
// Round-17 post-mortem: R (zero LDS, free-run) = 50us REGRESSION — barrier
// removal is not the lever; per-thread VMEM tripled. P2/P2b (~29.6us) is
// the confirmed local-best structure. Its remaining leak: reads trickle
// out in 5-load bursts per chunk, so HBM demand ramps instead of
// saturating, and each STAGE's vmcnt wait trails issue by only ~1 chunk.
// Per-CU unique bytes = 488KB (floor 16-20us) — no reason to trickle.
// Change (single axis: request-stream shape):
//  - Prologue issues the block's ENTIRE read set: 25 wk + 4x5 x-chunk
//    loads, in order [wk][A][B][C][D]. In-order vmcnt retirement then
//    makes waits incremental: STAGE(A) waits wk+A (wk is L2-fast, needed
//    immediately after anyway), STAGE(B)=vmcnt(10), STAGE(C)=vmcnt(5),
//    STAGE(D)=vmcnt(0) ~3 chunk-periods after issue. HBM pipe saturated
//    from t=0; steady state has zero extra instructions.
//  - No mid-loop ISSUEs. Chunk bodies: COMPUTE -> STAGE(next) ->
//    no-drain barrier -> STORE. Stores never drained (lgkmcnt-only
//    barrier, P2b-verified correct).
// VGPR audit: wk 100 + x sets 80 + acc 16 + soff/swo/sok 14 + addr ~12
// ~= 225 < 256 cap at (256,2). Spill tripwire: WRITE_SIZE must stay
// 32768KB; VGPR_Count 210-240 expected.
// Keep (frozen): PITCH=66 b64 reads, staged-zero OOB rows (exact jnp.pad),
// raw wk, zeroed guards/pads, grid 512 = 2 blocks/CU, halves in slow
// blockIdx bits (XCD w-sharing), 4-chunk full unroll, FMA order unchanged
// (absmax must stay 0.0).
// Decision rule: >=3us harness gain => MLP confirmed -> next: DS b128.
// Flat => concurrency exhausted -> test PITCH=68 b128, else plateau.

#define B_ 8
#define C_ 256
#define G_ 8
#define CG_ 32
#define H_ 64
#define W_ 64
#define K2_ 25
#define HW_ (H_ * W_)
#define NCH 4               // channels per chunk
#define NCHUNK 4            // chunks per block (half group = 16 channels)
#define NROWS 20            // 16-row band + 2 halo each side
#define PITCH 66            // 64 data + 2 pad words; stride == 2 mod 32 banks
#define CHSTRIDE 1322       // 2 guard words + 20*66
#define BUFW (NCH * CHSTRIDE)  // 5288 words = 21.2 KB per buffer

// no-drain block barrier: commit my LDS writes, then raw s_barrier.
// (__syncthreads would add s_waitcnt vmcnt(0) = full VMEM drain.)
#define BARRIER_NODRAIN()                                \
  {                                                      \
    asm volatile("s_waitcnt lgkmcnt(0)" ::: "memory");   \
    __builtin_amdgcn_s_barrier();                        \
  }

#define ISSUE(R0, R1, R2, R3, R4, CH)                    \
  {                                                      \
    const float* xn = xg + (size_t)(CH) * NCH * HW_;     \
    R0 = *(const float4*)(xn + soff[0]);                 \
    R1 = *(const float4*)(xn + soff[1]);                 \
    R2 = *(const float4*)(xn + soff[2]);                 \
    R3 = *(const float4*)(xn + soff[3]);                 \
    R4 = *(const float4*)(xn + soff[4]);                 \
  }

// OOB rows staged as exact 0 (= jnp.pad); cndmask consumes loads right at
// the ds_write, which is where the vmcnt wait belongs anyway.
#define STAGE(R0, R1, R2, R3, R4, PB)                                     \
  {                                                                       \
    const float4 z4 = make_float4(0.f, 0.f, 0.f, 0.f);                    \
    const float4 v0 = sok[0] ? R0 : z4;                                   \
    const float4 v1 = sok[1] ? R1 : z4;                                   \
    const float4 v2 = sok[2] ? R2 : z4;                                   \
    const float4 v3 = sok[3] ? R3 : z4;                                   \
    const float4 v4 = sok[4] ? R4 : z4;                                   \
    *(float2*)&lds[(PB) + swo[0]] = make_float2(v0.x, v0.y);              \
    *(float2*)&lds[(PB) + swo[0] + 2] = make_float2(v0.z, v0.w);          \
    *(float2*)&lds[(PB) + swo[1]] = make_float2(v1.x, v1.y);              \
    *(float2*)&lds[(PB) + swo[1] + 2] = make_float2(v1.z, v1.w);          \
    *(float2*)&lds[(PB) + swo[2]] = make_float2(v2.x, v2.y);              \
    *(float2*)&lds[(PB) + swo[2] + 2] = make_float2(v2.z, v2.w);          \
    *(float2*)&lds[(PB) + swo[3]] = make_float2(v3.x, v3.y);              \
    *(float2*)&lds[(PB) + swo[3] + 2] = make_float2(v3.z, v3.w);          \
    *(float2*)&lds[(PB) + swo[4]] = make_float2(v4.x, v4.y);              \
    *(float2*)&lds[(PB) + swo[4] + 2] = make_float2(v4.z, v4.w);          \
  }

// compute NCH channel quads from buf at word offset PB into acc[][]
#define COMPUTE(PB)                                                       \
  _Pragma("unroll") for (int c = 0; c < NCH; ++c) {                       \
    acc[c][0] = 0.f; acc[c][1] = 0.f; acc[c][2] = 0.f; acc[c][3] = 0.f;   \
  }                                                                       \
  _Pragma("unroll") for (int di = 0; di < 5; ++di) {                      \
    const int rbase = (PB) + (lr + di) * PITCH + wcol;                    \
    _Pragma("unroll") for (int c = 0; c < NCH; ++c) {                     \
      const int a0 = c * CHSTRIDE + rbase;                                \
      alignas(16) float xr[8];                                            \
      *(float2*)&xr[0] = *(const float2*)&lds[a0];                        \
      *(float2*)&xr[2] = *(const float2*)&lds[a0 + 2];                    \
      *(float2*)&xr[4] = *(const float2*)&lds[a0 + 4];                    \
      *(float2*)&xr[6] = *(const float2*)&lds[a0 + 6];                    \
      _Pragma("unroll") for (int dj = 0; dj < 5; ++dj) {                  \
        const float4 wv = wk[di * 5 + dj];                                \
        acc[c][0] = fmaf(xr[dj + 0], wv.x, acc[c][0]);                    \
        acc[c][1] = fmaf(xr[dj + 1], wv.y, acc[c][1]);                    \
        acc[c][2] = fmaf(xr[dj + 2], wv.z, acc[c][2]);                    \
        acc[c][3] = fmaf(xr[dj + 3], wv.w, acc[c][3]);                    \
      }                                                                   \
    }                                                                     \
  }

#define STORE(CH)                                                         \
  {                                                                       \
    float* ob = og + (size_t)(CH) * NCH * HW_;                            \
    *(float4*)(ob + (size_t)0 * HW_) = *(const float4*)acc[0];            \
    *(float4*)(ob + (size_t)1 * HW_) = *(const float4*)acc[1];            \
    *(float4*)(ob + (size_t)2 * HW_) = *(const float4*)acc[2];            \
    *(float4*)(ob + (size_t)3 * HW_) = *(const float4*)acc[3];            \
  }

__global__ __launch_bounds__(256, 2) void ska_kernel(
    const float* __restrict__ x, const float* __restrict__ w,
    float* __restrict__ out) {
  __shared__ __align__(16) float lds[2 * BUFW];  // 41.3 KB
  const int tid = threadIdx.x;
  const int lr = tid >> 4;   // output row within band (0..15)
  const int j = tid & 15;    // column quad (cols 4j..4j+3)
  const int wcol = j * 4;

  // blockIdx = [half(1) | b(3) | g(3) | band(2)], 512 blocks = 2 per CU.
  const int blk = blockIdx.x;
  const int band = blk & 3;
  const int g = (blk >> 2) & 7;
  const int b = (blk >> 5) & 7;
  const int half = blk >> 8;  // 0/1: which 16 channels of the group

  const int h0 = band * 16;
  const int h = h0 + lr;

  // ---- chunk-invariant staging slots: 5 per thread ----
  int soff[5];   // x word offset within chunk (c*HW + clamped_row*W + q*4)
  int swo[5];    // LDS word offset within buffer
  bool sok[5];   // row in bounds?
#pragma unroll
  for (int it = 0; it < 5; ++it) {
    const int i = tid + it * 256;
    const int c = i / 320;            // magic-mul
    const int rem = i - c * 320;
    const int rl = rem >> 4;          // window row 0..19
    const int q = rem & 15;           // column quad
    const int gr = h0 - 2 + rl;       // global row, may be OOB
    sok[it] = (unsigned)gr < (unsigned)H_;
    const int grc = min(max(gr, 0), H_ - 1);
    soff[it] = c * HW_ + grc * W_ + q * 4;
    swo[it] = c * CHSTRIDE + 2 + rl * PITCH + q * 4;  // 8B aligned
  }

  const size_t chanbase = (size_t)(b * C_ + g * CG_ + half * 16) * HW_;
  const float* xg = x + chanbase;
  float* og = out + chanbase + (size_t)h * W_ + wcol;

  // ---- prologue: issue the ENTIRE read set, in-order [wk][A][B][C][D] ----
  // wk oldest (L2-fast, needed first by COMPUTE(0)); x chunks follow so
  // each STAGE's implicit vmcnt wait is incremental (10/5/0).
  const float* wb =
      w + (size_t)(b * G_ + g) * K2_ * HW_ + (size_t)h * W_ + wcol;
  float4 wk[K2_];
#pragma unroll
  for (int k = 0; k < K2_; ++k)
    wk[k] = *(const float4*)(wb + (size_t)k * HW_);

  float4 a0, a1, a2, a3, a4;   // chunk 0
  float4 b0, b1, b2, b3, b4;   // chunk 1
  float4 c0, c1, c2, c3, c4;   // chunk 2
  float4 d0, d1, d2, d3, d4;   // chunk 3
  ISSUE(a0, a1, a2, a3, a4, 0)
  ISSUE(b0, b1, b2, b3, b4, 1)
  ISSUE(c0, c1, c2, c3, c4, 2)
  ISSUE(d0, d1, d2, d3, d4, 3)

  // ---- zero guards (2/ch) + row pads (2/row): 42 words x 4 ch, BOTH bufs ----
  if (tid < NCH * 42) {
    const int c = tid / 42;
    const int p = tid - c * 42;
    const int word =
        (p < 2) ? p : (2 + ((p - 2) >> 1) * PITCH + 64 + ((p - 2) & 1));
    lds[c * CHSTRIDE + word] = 0.0f;
    lds[BUFW + c * CHSTRIDE + word] = 0.0f;
  }

  STAGE(a0, a1, a2, a3, a4, 0)   // waits [wk]+[A] only (in-order vmcnt)
  BARRIER_NODRAIN()

  alignas(16) float acc[NCH][4];

  // ---- chunk 0: compute buf0; stage chunk1 -> buf1 ----
  COMPUTE(0)
  STAGE(b0, b1, b2, b3, b4, BUFW)
  BARRIER_NODRAIN()
  STORE(0)

  // ---- chunk 1: compute buf1; stage chunk2 -> buf0 ----
  COMPUTE(BUFW)
  STAGE(c0, c1, c2, c3, c4, 0)
  BARRIER_NODRAIN()
  STORE(1)

  // ---- chunk 2: compute buf0; stage chunk3 -> buf1 ----
  COMPUTE(0)
  STAGE(d0, d1, d2, d3, d4, BUFW)
  BARRIER_NODRAIN()
  STORE(2)

  // ---- chunk 3: compute buf1; store ----
  COMPUTE(BUFW)
  STORE(3)
}

extern "C" void kernel_launch(void* const* d_in, const int* in_sizes, int n_in,
                              void* d_out, int out_size, void* d_ws,
                              size_t ws_size, hipStream_t stream) {
  const float* x = (const float*)d_in[0];
  const float* w = (const float*)d_in[1];
  float* out = (float*)d_out;
  // grid: 2 halves * 8 b * 8 g * 4 bands = 512 blocks of 256 threads
  ska_kernel<<<dim3(512), dim3(256), 0, stream>>>(x, w, out);
}